// Round 15
// baseline (198.847 us; speedup 1.0000x reference)
//
#include <hip/hip_runtime.h>
#include <hip/hip_bf16.h>
#include <stdint.h>

#define NTOK 4096
#define DD 1024
#define EE 8
#define HH 2048
#define BM 128
#define BN 128
#define MAXRB 72
#define RPAD (MAXRB*BM)   // 9216 padded pair rows
#define GG1 (8*9*(HH/BN)) // 1152 gemm1 blocks
#define GG2 (8*9*(DD/BN)) // 576 gemm2 blocks

typedef __attribute__((ext_vector_type(4))) float f32x4;
typedef __attribute__((ext_vector_type(8))) short bf16x8;

__device__ __forceinline__ void gload16(const void* g, void* l) {
  __builtin_amdgcn_global_load_lds((const __attribute__((address_space(1))) unsigned int*)g,
                                   (__attribute__((address_space(3))) unsigned int*)l, 16, 0, 0);
}

__device__ __forceinline__ uint32_t pack_bf2(float lo, float hi) {
  return ((uint32_t)__bfloat16_as_ushort(__float2bfloat16(hi)) << 16)
       |  (uint32_t)__bfloat16_as_ushort(__float2bfloat16(lo));
}

// -------- transpose + f32->bf16 via u32 pair-packing; float4 (16B/lane) reads ----
__device__ __forceinline__ void transpose_body(uint32_t (*T)[33],
    const float* __restrict__ in, __hip_bfloat16* __restrict__ out,
    int R, int C, int tb) {
  int tilesC = C >> 6;
  int tilesPerE = (R >> 6) * tilesC;
  int e = tb / tilesPerE;
  int rem = tb % tilesPerE;
  int tr = rem / tilesC, tc = rem % tilesC;
  const float* src = in + (size_t)e * R * C + (size_t)(tr*64) * C + tc*64;
  int tid = threadIdx.x;
  int c4 = (tid & 15) << 2;
  int r2 = tid >> 4;
  #pragma unroll
  for (int i = 0; i < 2; ++i) {
    int r = r2 + (i << 4);
    const float* p0 = src + (size_t)(2*r) * C + c4;
    float4 a = *(const float4*)p0;
    float4 b = *(const float4*)(p0 + C);
    T[c4+0][r] = pack_bf2(a.x, b.x);
    T[c4+1][r] = pack_bf2(a.y, b.y);
    T[c4+2][r] = pack_bf2(a.z, b.z);
    T[c4+3][r] = pack_bf2(a.w, b.w);
  }
  __syncthreads();
  __hip_bfloat16* dst = out + (size_t)e * R * C + (size_t)(tc*64) * R + tr*64;
  int c  = tid >> 2;
  int ch = (tid & 3) * 8;
  uint32_t v[8];
  #pragma unroll
  for (int j = 0; j < 8; ++j) v[j] = T[c][ch + j];
  uint32_t* dp = (uint32_t*)(dst + (size_t)c * R + ch*2);
  #pragma unroll
  for (int j = 0; j < 8; ++j) dp[j] = v[j];
}

// ---- mega: router+top2 (blocks 0..4095) + W1 transpose (4096..8191) ----
__global__ __launch_bounds__(256) void mega_kernel(const float* __restrict__ x,
    const float* __restrict__ Wg,
    int* __restrict__ topE, float* __restrict__ topW, int* __restrict__ counts64,
    const float* __restrict__ W1, __hip_bfloat16* __restrict__ W1bT) {
  __shared__ __align__(16) char smem[8448];
  int b = blockIdx.x;
  if (b < NTOK) {
    int t = b;
    int tid = threadIdx.x;
    const float* xr = x + (size_t)t * DD;
    double acc[EE];
    #pragma unroll
    for (int e = 0; e < EE; ++e) acc[e] = 0.0;
    #pragma unroll
    for (int i = 0; i < DD/256; ++i) {
      int d = tid + i*256;
      float xv = xr[d];
      float4 w0 = *(const float4*)(Wg + (size_t)d*EE);
      float4 w1 = *(const float4*)(Wg + (size_t)d*EE + 4);
      double xd = (double)xv;
      acc[0] += xd * (double)w0.x; acc[1] += xd * (double)w0.y;
      acc[2] += xd * (double)w0.z; acc[3] += xd * (double)w0.w;
      acc[4] += xd * (double)w1.x; acc[5] += xd * (double)w1.y;
      acc[6] += xd * (double)w1.z; acc[7] += xd * (double)w1.w;
    }
    #pragma unroll
    for (int e = 0; e < EE; ++e) {
      double v = acc[e];
      #pragma unroll
      for (int off = 32; off > 0; off >>= 1) v += __shfl_down(v, off, 64);
      acc[e] = v;
    }
    double (*sAcc)[EE] = (double(*)[EE])smem;
    int lane = tid & 63, w = tid >> 6;
    if (lane == 0) {
      #pragma unroll
      for (int e = 0; e < EE; ++e) sAcc[w][e] = acc[e];
    }
    __syncthreads();
    if (tid == 0) {
      double s[EE];
      #pragma unroll
      for (int e = 0; e < EE; ++e)
        s[e] = sAcc[0][e] + sAcc[1][e] + sAcc[2][e] + sAcc[3][e];
      double mx = s[0];
      #pragma unroll
      for (int e = 1; e < EE; ++e) mx = fmax(mx, s[e]);
      double p[EE], Z = 0.0;
      #pragma unroll
      for (int e = 0; e < EE; ++e) { p[e] = exp(s[e] - mx); Z += p[e]; }
      #pragma unroll
      for (int e = 0; e < EE; ++e) p[e] /= Z;
      int i0 = 0;
      #pragma unroll
      for (int e = 1; e < EE; ++e) if (p[e] > p[i0]) i0 = e;
      int i1 = -1;
      #pragma unroll
      for (int e = 0; e < EE; ++e) { if (e == i0) continue; if (i1 < 0 || p[e] > p[i1]) i1 = e; }
      double sm = p[i0] + p[i1] + 1e-8;
      topE[t*2]   = i0; topE[t*2+1] = i1;
      topW[t*2]   = (float)(p[i0] / sm);
      topW[t*2+1] = (float)(p[i1] / sm);
      int slot = (b & 63) * 16;
      atomicAdd(&counts64[slot + i0], 1);
      atomicAdd(&counts64[slot + i1], 1);
    }
  } else {
    transpose_body((uint32_t(*)[33])smem, W1, W1bT, DD, HH, b - NTOK);
  }
}

// -------- setup (counts64 reduce + 128-row padding) + slot assignment: 1 block -----
__global__ __launch_bounds__(1024) void assign_kernel(const int* __restrict__ counts64,
    const int* __restrict__ topE, const float* __restrict__ topW,
    int* __restrict__ po, int* __restrict__ nRB, int* __restrict__ rbExpert,
    int* __restrict__ pairsTok, float* __restrict__ pairsW, int* __restrict__ slotOf) {
  __shared__ int cnt[EE];
  __shared__ int base[EE];
  __shared__ int wcnt[16][EE];
  int tid = threadIdx.x, wv = tid >> 6, lane = tid & 63;
  if (tid < EE) {
    int s = 0;
    #pragma unroll
    for (int k = 0; k < 64; ++k) s += counts64[k*16 + tid];
    cnt[tid] = s;
  }
  for (int i = tid; i < RPAD; i += 1024) pairsTok[i] = -1;
  __syncthreads();
  if (tid == 0) {
    int off = 0;
    for (int e = 0; e < EE; ++e) {
      po[e] = off;
      off += ((cnt[e] + BM - 1) / BM) * BM;
    }
    po[EE] = off;
    *nRB = off / BM;
    int rb = 0;
    for (int e = 0; e < EE; ++e) {
      int nb = (cnt[e] + BM - 1) / BM;
      for (int b = 0; b < nb; ++b) rbExpert[rb++] = e;
    }
  }
  __syncthreads();
  if (tid < EE) base[tid] = po[tid];
  __syncthreads();
  for (int it = 0; it < 2*NTOK/1024; ++it) {
    int p = it*1024 + tid;
    int e = topE[p];
    int myrank = 0;
    #pragma unroll
    for (int ee = 0; ee < EE; ++ee) {
      unsigned long long b = __ballot(e == ee);
      if (ee == e) myrank = __popcll(b & ((1ull << lane) - 1ull));
      if (lane == 0) wcnt[wv][ee] = __popcll(b);
    }
    __syncthreads();
    int wbase = 0;
    for (int w2 = 0; w2 < wv; ++w2) wbase += wcnt[w2][e];
    int slot = base[e] + wbase + myrank;
    pairsTok[slot] = p >> 1;
    pairsW[slot]   = topW[p];
    slotOf[p]      = slot;
    __syncthreads();
    if (tid < EE) {
      int s2 = 0;
      #pragma unroll
      for (int w2 = 0; w2 < 16; ++w2) s2 += wcnt[w2][tid];
      base[tid] += s2;
    }
    __syncthreads();
  }
}

// ---------------- gather x rows to bf16 at assigned slots ----------------
__global__ __launch_bounds__(256) void gather_kernel(const float* __restrict__ x,
    const int* __restrict__ slotOf, __hip_bfloat16* __restrict__ Xg) {
  int t = blockIdx.x;
  int s0 = slotOf[2*t], s1 = slotOf[2*t+1];
  const float* xr = x + (size_t)t * DD;
  int i = threadIdx.x;
  float4 v = ((const float4*)xr)[i];
  ushort4 b;
  b.x = __bfloat16_as_ushort(__float2bfloat16(v.x));
  b.y = __bfloat16_as_ushort(__float2bfloat16(v.y));
  b.z = __bfloat16_as_ushort(__float2bfloat16(v.z));
  b.w = __bfloat16_as_ushort(__float2bfloat16(v.w));
  ((ushort4*)(Xg + (size_t)s0 * DD))[i] = b;
  ((ushort4*)(Xg + (size_t)s1 * DD))[i] = b;
}

// ---- grouped GEMM body, 128x128 tile, BK=32, TRUE 2-deep dbuf at UNCHANGED
// ---- occupancy: 2 x 16KB buffers = 32KB (same as old single-buffer 33KB ->
// ---- still 4 blocks/CU). Raw s_barrier + COUNTED vmcnt(4): tile kt+1's loads
// ---- stay in flight across COMPUTE(kt); never drain to 0 mid-loop (T4).
// LDS rows are 64B (4x16B slots); XOR swizzle slot ^= (row>>1)&3 on BOTH the
// pre-swizzled global source and the ds_read -> max 2-way bank alias (free).
// smem: buf0 A[0..8K) B[8K..16K), buf1 [16K..32K), sTok @32K, sW @32.5K
template<int EPI, int KDIM, int NTOT>
__device__ __forceinline__ void gemm_body(char* smem, int bid,
    const __hip_bfloat16* __restrict__ A, const __hip_bfloat16* __restrict__ Ball,
    __hip_bfloat16* __restrict__ Cbf, float* __restrict__ Cf,
    const int* __restrict__ nRB, const int* __restrict__ rbExpert,
    const int* __restrict__ pairsTok, const float* __restrict__ pairsW) {
  int nrb = *nRB;
  int cpx = (nrb + 7) >> 3;
  int xcd = bid & 7;
  int slot = bid >> 3;
  int lr = slot % 9;
  int nb = slot / 9;
  int rb = xcd * cpx + lr;
  if (lr >= cpx || rb >= nrb) return;
  int e = rbExpert[rb];
  const __hip_bfloat16* Ag = A + (size_t)rb * BM * KDIM;
  const __hip_bfloat16* Bg = Ball + (size_t)e * NTOT * KDIM + (size_t)nb * BN * KDIM;
  int*   sTok = (int*)(smem + 32768);
  float* sW   = (float*)(smem + 32768 + 512);
  int tid = threadIdx.x;
  if (EPI == 1 && tid < BM) {
    sTok[tid] = pairsTok[rb*BM + tid];
    sW[tid]   = pairsW[rb*BM + tid];
  }
  int lane = tid & 63;
  int wid = tid >> 6;
  int wr = wid >> 1, wc = wid & 1;
  int l15 = lane & 15;
  int lhi = lane >> 4;
  f32x4 acc[4][4] = {};
  int srow4  = tid >> 2;        // 0..63 (staging row base)
  int scol16 = tid & 3;         // 16B slot within 64B row

  // stage tile kt into buffer buf: 2 chunks x (A row + B row), 4 gload16/thread
  #define STAGE(buf, kt) {                                                        \
    _Pragma("unroll")                                                             \
    for (int i = 0; i < 2; ++i) {                                                 \
      int row = srow4 + 64*i;                                                     \
      int sc = 8 * (scol16 ^ ((row >> 1) & 3));   /* pre-swizzled source elems */ \
      gload16(Ag + (size_t)row * KDIM + (kt)*32 + sc,                             \
              smem + (buf)*16384 + i*4096 + tid*16);                              \
      gload16(Bg + (size_t)row * KDIM + (kt)*32 + sc,                             \
              smem + (buf)*16384 + 8192 + i*4096 + tid*16);                       \
    } }

  #define COMPUTE(buf) {                                                          \
    bf16x8 af[4], bfr[4];                                                         \
    _Pragma("unroll")                                                             \
    for (int m = 0; m < 4; ++m) {                                                 \
      int row = wr*64 + m*16 + l15;                                               \
      af[m] = *(const bf16x8*)(smem + (buf)*16384 + row*64 +                      \
                               ((lhi*16) ^ (((row >> 1) & 3) << 4)));             \
    }                                                                             \
    _Pragma("unroll")                                                             \
    for (int n = 0; n < 4; ++n) {                                                 \
      int row = wc*64 + n*16 + l15;                                               \
      bfr[n] = *(const bf16x8*)(smem + (buf)*16384 + 8192 + row*64 +              \
                                ((lhi*16) ^ (((row >> 1) & 3) << 4)));            \
    }                                                                             \
    _Pragma("unroll")                                                             \
    for (int m = 0; m < 4; ++m)                                                   \
      _Pragma("unroll")                                                           \
      for (int n = 0; n < 4; ++n)                                                 \
        acc[m][n] = __builtin_amdgcn_mfma_f32_16x16x32_bf16(af[m], bfr[n],        \
                                                            acc[m][n], 0, 0, 0); \
    }

  constexpr int NT = KDIM / 32;
  STAGE(0, 0);
  for (int kt = 0; kt < NT; ++kt) {
    if (kt + 1 < NT) {
      STAGE((kt + 1) & 1, kt + 1);                      // fly under COMPUTE(kt)
      asm volatile("s_waitcnt vmcnt(4)" ::: "memory");  // my tile-kt loads landed
    } else {
      asm volatile("s_waitcnt vmcnt(0)" ::: "memory");
    }
    __builtin_amdgcn_s_barrier();    // everyone's tile-kt loads landed
    COMPUTE(kt & 1);
    __builtin_amdgcn_s_barrier();    // all reads of buf kt&1 done -> safe to restage
  }
  #undef STAGE
  #undef COMPUTE

  if (EPI == 0) {
    #pragma unroll
    for (int m = 0; m < 4; ++m) {
      int row = rb*BM + wr*64 + m*16 + lhi*4;
      #pragma unroll
      for (int n = 0; n < 4; ++n) {
        int col = nb*BN + wc*64 + n*16 + l15;
        #pragma unroll
        for (int j = 0; j < 4; ++j) {
          float v = fmaxf(acc[m][n][j], 0.0f);
          Cbf[(size_t)(row + j) * NTOT + col] = __float2bfloat16(v * v);
        }
      }
    }
  } else {
    #pragma unroll
    for (int m = 0; m < 4; ++m) {
      int rloc = wr*64 + m*16 + lhi*4;
      #pragma unroll
      for (int j = 0; j < 4; ++j) {
        int tok = sTok[rloc + j];
        if (tok < 0) continue;
        float w = sW[rloc + j];
        #pragma unroll
        for (int n = 0; n < 4; ++n) {
          int col = nb*BN + wc*64 + n*16 + l15;
          atomicAdd(Cf + (size_t)tok * NTOT + col, w * acc[m][n][j]);
        }
      }
    }
  }
}

// ---- GEMM1 fused with W2 transpose: blocks [0,GG1) = gemm, [GG1,GG1+4096) = W2T.
__global__ __launch_bounds__(256, 4)
void gemm1_fused(const __hip_bfloat16* __restrict__ Xg,
                 const __hip_bfloat16* __restrict__ W1bT,
                 __hip_bfloat16* __restrict__ Hbuf,
                 const int* __restrict__ nRB, const int* __restrict__ rbExpert,
                 const int* __restrict__ pairsTok, const float* __restrict__ pairsW,
                 const float* __restrict__ W2, __hip_bfloat16* __restrict__ W2bT) {
  __shared__ __align__(16) char smem[33*1024 + 1024];
  int bid = blockIdx.x;
  if (bid < GG1) {
    gemm_body<0, DD, HH>(smem, bid, Xg, W1bT, Hbuf, nullptr,
                         nRB, rbExpert, pairsTok, pairsW);
  } else {
    transpose_body((uint32_t(*)[33])smem, W2, W2bT, HH, DD, bid - GG1);
  }
}

__global__ __launch_bounds__(256, 4)
void gemm2_kernel(const __hip_bfloat16* __restrict__ Hbuf,
                  const __hip_bfloat16* __restrict__ W2bT,
                  float* __restrict__ out,
                  const int* __restrict__ nRB, const int* __restrict__ rbExpert,
                  const int* __restrict__ pairsTok, const float* __restrict__ pairsW) {
  __shared__ __align__(16) char smem[33*1024 + 1024];
  gemm_body<1, HH, DD>(smem, blockIdx.x, Hbuf, W2bT, nullptr, out,
                       nRB, rbExpert, pairsTok, pairsW);
}

// ---------------- workspace layout (bytes) ----------------
// 128    po[9]; 192 nRB; 256 rbExpert[72]
// 4096   counts64[64][16] (64-byte strided counters)
// 40960  topW[8192]
// 73728  pairsTok[9216]
// 110592 pairsW[9216]
// 147456 slotOf[8192]
// 180224 topE[8192]
// 262144 Xg      [9216][1024] bf16
// 19136512 Hbuf  [9216][2048] bf16
// 56885248 W1bT  [8][2048][1024] bf16
// 90439680 W2bT  [8][1024][2048] bf16

extern "C" void kernel_launch(void* const* d_in, const int* in_sizes, int n_in,
                              void* d_out, int out_size, void* d_ws, size_t ws_size,
                              hipStream_t stream) {
  const float* x  = (const float*)d_in[0];
  const float* Wg = (const float*)d_in[1];
  const float* W1 = (const float*)d_in[2];
  const float* W2 = (const float*)d_in[3];
  float* out = (float*)d_out;
  char* ws = (char*)d_ws;

  int*   po       = (int*)(ws + 128);
  int*   nRB      = (int*)(ws + 192);
  int*   rbExpert = (int*)(ws + 256);
  int*   counts64 = (int*)(ws + 4096);
  float* topW     = (float*)(ws + 40960);
  int*   pairsTok = (int*)(ws + 73728);
  float* pairsW   = (float*)(ws + 110592);
  int*   slotOf   = (int*)(ws + 147456);
  int*   topE     = (int*)(ws + 180224);
  __hip_bfloat16* Xg   = (__hip_bfloat16*)(ws + 262144);
  __hip_bfloat16* Hbuf = (__hip_bfloat16*)(ws + 19136512);
  __hip_bfloat16* W1bT = (__hip_bfloat16*)(ws + 56885248);
  __hip_bfloat16* W2bT = (__hip_bfloat16*)(ws + 90439680);

  hipMemsetAsync(d_out, 0, (size_t)out_size * sizeof(float), stream);
  hipMemsetAsync(ws, 0, 8192, stream);   // po/nRB + counts64

  mega_kernel<<<NTOK + 4096, 256, 0, stream>>>(x, Wg, topE, topW, counts64, W1, W1bT);
  assign_kernel<<<1, 1024, 0, stream>>>(counts64, topE, topW, po, nRB, rbExpert,
                                        pairsTok, pairsW, slotOf);
  gather_kernel<<<NTOK, 256, 0, stream>>>(x, slotOf, Xg);

  gemm1_fused<<<GG1 + 4096, 256, 0, stream>>>(Xg, W1bT, Hbuf, nRB, rbExpert,
                                              pairsTok, pairsW, W2, W2bT);
  gemm2_kernel<<<GG2, 256, 0, stream>>>(Hbuf, W2bT, out, nRB, rbExpert,
                                        pairsTok, pairsW);
}

// Round 16
// 191.549 us; speedup vs baseline: 1.0381x; 1.0381x over previous
//
#include <hip/hip_runtime.h>
#include <hip/hip_bf16.h>
#include <stdint.h>

#define NTOK 4096
#define DD 1024
#define EE 8
#define HH 2048
#define BM 128
#define BN 128
#define BK 64
#define MAXRB 72
#define RPAD (MAXRB*BM)   // 9216 padded pair rows
#define GG1 (8*9*(HH/BN)) // 1152 gemm1 blocks
#define GG2 (8*9*(DD/BN)) // 576 gemm2 blocks

typedef __attribute__((ext_vector_type(4))) float f32x4;
typedef __attribute__((ext_vector_type(8))) short bf16x8;

__device__ __forceinline__ void gload16(const void* g, void* l) {
  __builtin_amdgcn_global_load_lds((const __attribute__((address_space(1))) unsigned int*)g,
                                   (__attribute__((address_space(3))) unsigned int*)l, 16, 0, 0);
}

__device__ __forceinline__ uint32_t pack_bf2(float lo, float hi) {
  return ((uint32_t)__bfloat16_as_ushort(__float2bfloat16(hi)) << 16)
       |  (uint32_t)__bfloat16_as_ushort(__float2bfloat16(lo));
}

// -------- transpose + f32->bf16 via u32 pair-packing; float4 (16B/lane) reads ----
// in [E][R][C] -> out [E][C][R]. T[c][r/2] = bf16(row 2r)|bf16(row 2r+1).
// Write banks: T[c4+j][r], 4 consecutive banks/lane, wave spread = 2-way (free).
// Read: 8 contiguous u32 -> 2x ds_read_b128 conflict-free; 32B coalesced stores.
__device__ __forceinline__ void transpose_body(uint32_t (*T)[33],
    const float* __restrict__ in, __hip_bfloat16* __restrict__ out,
    int R, int C, int tb) {
  int tilesC = C >> 6;
  int tilesPerE = (R >> 6) * tilesC;
  int e = tb / tilesPerE;
  int rem = tb % tilesPerE;
  int tr = rem / tilesC, tc = rem % tilesC;
  const float* src = in + (size_t)e * R * C + (size_t)(tr*64) * C + tc*64;
  int tid = threadIdx.x;
  int c4 = (tid & 15) << 2;   // 0..60
  int r2 = tid >> 4;          // 0..15
  #pragma unroll
  for (int i = 0; i < 2; ++i) {
    int r = r2 + (i << 4);    // 0..31 -> input rows 2r, 2r+1
    const float* p0 = src + (size_t)(2*r) * C + c4;
    float4 a = *(const float4*)p0;        // row 2r, cols c4..c4+3
    float4 b = *(const float4*)(p0 + C);  // row 2r+1
    T[c4+0][r] = pack_bf2(a.x, b.x);
    T[c4+1][r] = pack_bf2(a.y, b.y);
    T[c4+2][r] = pack_bf2(a.z, b.z);
    T[c4+3][r] = pack_bf2(a.w, b.w);
  }
  __syncthreads();
  __hip_bfloat16* dst = out + (size_t)e * R * C + (size_t)(tc*64) * R + tr*64;
  int c  = tid >> 2;
  int ch = (tid & 3) * 8;
  uint32_t v[8];
  #pragma unroll
  for (int j = 0; j < 8; ++j) v[j] = T[c][ch + j];   // 2x ds_read_b128
  uint32_t* dp = (uint32_t*)(dst + (size_t)c * R + ch*2);
  #pragma unroll
  for (int j = 0; j < 8; ++j) dp[j] = v[j];          // 32B coalesced store
}

// ---- mega: router+top2 (blocks 0..4095) + W1 transpose (4096..8191) ----
// Router block computes f64 logits, then thread 0 does softmax/top-2/renorm
// inline and histograms into 64-way cacheline-strided counters
// (counts64[(bid&63)*16+e]) -> no same-line atomic pileup (R1/R2 lesson).
__global__ __launch_bounds__(256) void mega_kernel(const float* __restrict__ x,
    const float* __restrict__ Wg,
    int* __restrict__ topE, float* __restrict__ topW, int* __restrict__ counts64,
    const float* __restrict__ W1, __hip_bfloat16* __restrict__ W1bT) {
  __shared__ __align__(16) char smem[8448];
  int b = blockIdx.x;
  if (b < NTOK) {
    int t = b;
    int tid = threadIdx.x;
    const float* xr = x + (size_t)t * DD;
    double acc[EE];
    #pragma unroll
    for (int e = 0; e < EE; ++e) acc[e] = 0.0;
    #pragma unroll
    for (int i = 0; i < DD/256; ++i) {
      int d = tid + i*256;
      float xv = xr[d];
      float4 w0 = *(const float4*)(Wg + (size_t)d*EE);
      float4 w1 = *(const float4*)(Wg + (size_t)d*EE + 4);
      double xd = (double)xv;
      acc[0] += xd * (double)w0.x; acc[1] += xd * (double)w0.y;
      acc[2] += xd * (double)w0.z; acc[3] += xd * (double)w0.w;
      acc[4] += xd * (double)w1.x; acc[5] += xd * (double)w1.y;
      acc[6] += xd * (double)w1.z; acc[7] += xd * (double)w1.w;
    }
    #pragma unroll
    for (int e = 0; e < EE; ++e) {
      double v = acc[e];
      #pragma unroll
      for (int off = 32; off > 0; off >>= 1) v += __shfl_down(v, off, 64);
      acc[e] = v;
    }
    double (*sAcc)[EE] = (double(*)[EE])smem;
    int lane = tid & 63, w = tid >> 6;
    if (lane == 0) {
      #pragma unroll
      for (int e = 0; e < EE; ++e) sAcc[w][e] = acc[e];
    }
    __syncthreads();
    if (tid == 0) {
      double s[EE];
      #pragma unroll
      for (int e = 0; e < EE; ++e)
        s[e] = sAcc[0][e] + sAcc[1][e] + sAcc[2][e] + sAcc[3][e];
      double mx = s[0];
      #pragma unroll
      for (int e = 1; e < EE; ++e) mx = fmax(mx, s[e]);
      double p[EE], Z = 0.0;
      #pragma unroll
      for (int e = 0; e < EE; ++e) { p[e] = exp(s[e] - mx); Z += p[e]; }
      #pragma unroll
      for (int e = 0; e < EE; ++e) p[e] /= Z;
      int i0 = 0;
      #pragma unroll
      for (int e = 1; e < EE; ++e) if (p[e] > p[i0]) i0 = e;
      int i1 = -1;
      #pragma unroll
      for (int e = 0; e < EE; ++e) { if (e == i0) continue; if (i1 < 0 || p[e] > p[i1]) i1 = e; }
      double sm = p[i0] + p[i1] + 1e-8;
      topE[t*2]   = i0; topE[t*2+1] = i1;
      topW[t*2]   = (float)(p[i0] / sm);
      topW[t*2+1] = (float)(p[i1] / sm);
      int slot = (b & 63) * 16;
      atomicAdd(&counts64[slot + i0], 1);
      atomicAdd(&counts64[slot + i1], 1);
    }
  } else {
    transpose_body((uint32_t(*)[33])smem, W1, W1bT, DD, HH, b - NTOK);
  }
}

// -------- setup (counts64 reduce + 128-row padding) + slot assignment: 1 block -----
__global__ __launch_bounds__(1024) void assign_kernel(const int* __restrict__ counts64,
    const int* __restrict__ topE, const float* __restrict__ topW,
    int* __restrict__ po, int* __restrict__ nRB, int* __restrict__ rbExpert,
    int* __restrict__ pairsTok, float* __restrict__ pairsW, int* __restrict__ slotOf) {
  __shared__ int cnt[EE];
  __shared__ int base[EE];
  __shared__ int wcnt[16][EE];
  int tid = threadIdx.x, wv = tid >> 6, lane = tid & 63;
  if (tid < EE) {
    int s = 0;
    #pragma unroll
    for (int k = 0; k < 64; ++k) s += counts64[k*16 + tid];
    cnt[tid] = s;
  }
  for (int i = tid; i < RPAD; i += 1024) pairsTok[i] = -1;
  __syncthreads();
  if (tid == 0) {
    int off = 0;
    for (int e = 0; e < EE; ++e) {
      po[e] = off;
      off += ((cnt[e] + BM - 1) / BM) * BM;
    }
    po[EE] = off;
    *nRB = off / BM;
    int rb = 0;
    for (int e = 0; e < EE; ++e) {
      int nb = (cnt[e] + BM - 1) / BM;
      for (int b = 0; b < nb; ++b) rbExpert[rb++] = e;
    }
  }
  __syncthreads();
  if (tid < EE) base[tid] = po[tid];
  __syncthreads();
  for (int it = 0; it < 2*NTOK/1024; ++it) {
    int p = it*1024 + tid;
    int e = topE[p];
    int myrank = 0;
    #pragma unroll
    for (int ee = 0; ee < EE; ++ee) {
      unsigned long long b = __ballot(e == ee);
      if (ee == e) myrank = __popcll(b & ((1ull << lane) - 1ull));
      if (lane == 0) wcnt[wv][ee] = __popcll(b);
    }
    __syncthreads();
    int wbase = 0;
    for (int w2 = 0; w2 < wv; ++w2) wbase += wcnt[w2][e];
    int slot = base[e] + wbase + myrank;
    pairsTok[slot] = p >> 1;
    pairsW[slot]   = topW[p];
    slotOf[p]      = slot;
    __syncthreads();
    if (tid < EE) {
      int s2 = 0;
      #pragma unroll
      for (int w2 = 0; w2 < 16; ++w2) s2 += wcnt[w2][tid];
      base[tid] += s2;
    }
    __syncthreads();
  }
}

// ---------------- gather x rows to bf16 at assigned slots ----------------
__global__ __launch_bounds__(256) void gather_kernel(const float* __restrict__ x,
    const int* __restrict__ slotOf, __hip_bfloat16* __restrict__ Xg) {
  int t = blockIdx.x;
  int s0 = slotOf[2*t], s1 = slotOf[2*t+1];
  const float* xr = x + (size_t)t * DD;
  int i = threadIdx.x;
  float4 v = ((const float4*)xr)[i];
  ushort4 b;
  b.x = __bfloat16_as_ushort(__float2bfloat16(v.x));
  b.y = __bfloat16_as_ushort(__float2bfloat16(v.y));
  b.z = __bfloat16_as_ushort(__float2bfloat16(v.z));
  b.w = __bfloat16_as_ushort(__float2bfloat16(v.w));
  ((ushort4*)(Xg + (size_t)s0 * DD))[i] = b;
  ((ushort4*)(Xg + (size_t)s1 * DD))[i] = b;
}

// ---- grouped GEMM body, 128x128 tile, BK=64, single-buffer (R6/R10-proven),
// ---- balanced XCD chunking. smem: As[0..16K), Bs[16K..32K), sTok, sW.
// NOTE (session evidence): this 2-barrier single-buffer loop at 4 blocks/CU is
// the measured optimum of its family. Beaten variants: sync-dbuf@2blk (98us),
// raw-barrier-dbuf@2blk (90us), counted-vmcnt BK=32 dbuf@4blk (77us, FETCH 2x:
// 64B/row sub-cacheline staging), BN=64 (flat), K-split (worse), producer-
// consumer fusion (worse). Occupancy/TLP knobs don't move the ~69us fixed point.
template<int EPI, int KDIM, int NTOT>
__device__ __forceinline__ void gemm_body(char* smem, int bid,
    const __hip_bfloat16* __restrict__ A, const __hip_bfloat16* __restrict__ Ball,
    __hip_bfloat16* __restrict__ Cbf, float* __restrict__ Cf,
    const int* __restrict__ nRB, const int* __restrict__ rbExpert,
    const int* __restrict__ pairsTok, const float* __restrict__ pairsW) {
  int nrb = *nRB;
  int cpx = (nrb + 7) >> 3;
  int xcd = bid & 7;
  int slot = bid >> 3;
  int lr = slot % 9;
  int nb = slot / 9;
  int rb = xcd * cpx + lr;
  if (lr >= cpx || rb >= nrb) return;
  int e = rbExpert[rb];
  const __hip_bfloat16* Ag = A + (size_t)rb * BM * KDIM;
  const __hip_bfloat16* Bg = Ball + (size_t)e * NTOT * KDIM + (size_t)nb * BN * KDIM;
  __hip_bfloat16* As = (__hip_bfloat16*)smem;
  __hip_bfloat16* Bs = (__hip_bfloat16*)(smem + 16384);
  int*   sTok = (int*)(smem + 32768);
  float* sW   = (float*)(smem + 32768 + 512);
  int tid = threadIdx.x;
  if (EPI == 1 && tid < BM) {
    sTok[tid] = pairsTok[rb*BM + tid];
    sW[tid]   = pairsW[rb*BM + tid];
  }
  int lane = tid & 63;
  int wid = tid >> 6;
  int wr = wid >> 1, wc = wid & 1;
  int l15 = lane & 15;
  int lhi = lane >> 4;
  f32x4 acc[4][4] = {};
  int srow  = tid >> 3;
  int scol8 = (tid & 7) * 8;
  for (int kt = 0; kt < KDIM / BK; ++kt) {
    #pragma unroll
    for (int i = 0; i < 4; ++i) {
      int r = srow + 32*i;
      int sc = scol8 ^ ((r & 7) << 3);   // pre-swizzled global source
      gload16(Ag + (size_t)r * KDIM + kt*BK + sc, (char*)As + i*4096 + tid*16);
      gload16(Bg + (size_t)r * KDIM + kt*BK + sc, (char*)Bs + i*4096 + tid*16);
    }
    __syncthreads();
    #pragma unroll
    for (int kk = 0; kk < 2; ++kk) {
      bf16x8 af[4], bfr[4];
      int kb = kk*64 + lhi*16;
      #pragma unroll
      for (int m = 0; m < 4; ++m) {
        int row = wr*64 + m*16 + l15;
        af[m] = *(const bf16x8*)((const char*)As + row*128 + (kb ^ ((row & 7) << 4)));
      }
      #pragma unroll
      for (int n = 0; n < 4; ++n) {
        int row = wc*64 + n*16 + l15;
        bfr[n] = *(const bf16x8*)((const char*)Bs + row*128 + (kb ^ ((row & 7) << 4)));
      }
      #pragma unroll
      for (int m = 0; m < 4; ++m)
        #pragma unroll
        for (int n = 0; n < 4; ++n)
          acc[m][n] = __builtin_amdgcn_mfma_f32_16x16x32_bf16(af[m], bfr[n], acc[m][n], 0, 0, 0);
    }
    __syncthreads();
  }
  if (EPI == 0) {
    #pragma unroll
    for (int m = 0; m < 4; ++m) {
      int row = rb*BM + wr*64 + m*16 + lhi*4;
      #pragma unroll
      for (int n = 0; n < 4; ++n) {
        int col = nb*BN + wc*64 + n*16 + l15;
        #pragma unroll
        for (int j = 0; j < 4; ++j) {
          float v = fmaxf(acc[m][n][j], 0.0f);
          Cbf[(size_t)(row + j) * NTOT + col] = __float2bfloat16(v * v);
        }
      }
    }
  } else {
    #pragma unroll
    for (int m = 0; m < 4; ++m) {
      int rloc = wr*64 + m*16 + lhi*4;
      #pragma unroll
      for (int j = 0; j < 4; ++j) {
        int tok = sTok[rloc + j];
        if (tok < 0) continue;
        float w = sW[rloc + j];
        #pragma unroll
        for (int n = 0; n < 4; ++n) {
          int col = nb*BN + wc*64 + n*16 + l15;
          atomicAdd(Cf + (size_t)tok * NTOT + col, w * acc[m][n][j]);
        }
      }
    }
  }
}

// ---- GEMM1 fused with W2 transpose: blocks [0,GG1) = gemm, [GG1,GG1+4096) = W2T.
// GEMM1 is latency-bound at ~9% HBM; the W2 transpose (~96MB pure BW) rides in its
// idle bandwidth instead of a serial dispatch. Shared mem unioned (33.5KB).
__global__ __launch_bounds__(256, 4)
void gemm1_fused(const __hip_bfloat16* __restrict__ Xg,
                 const __hip_bfloat16* __restrict__ W1bT,
                 __hip_bfloat16* __restrict__ Hbuf,
                 const int* __restrict__ nRB, const int* __restrict__ rbExpert,
                 const int* __restrict__ pairsTok, const float* __restrict__ pairsW,
                 const float* __restrict__ W2, __hip_bfloat16* __restrict__ W2bT) {
  __shared__ __align__(16) char smem[33*1024 + 1024];
  int bid = blockIdx.x;
  if (bid < GG1) {
    gemm_body<0, DD, HH>(smem, bid, Xg, W1bT, Hbuf, nullptr,
                         nRB, rbExpert, pairsTok, pairsW);
  } else {
    transpose_body((uint32_t(*)[33])smem, W2, W2bT, HH, DD, bid - GG1);
  }
}

__global__ __launch_bounds__(256, 4)
void gemm2_kernel(const __hip_bfloat16* __restrict__ Hbuf,
                  const __hip_bfloat16* __restrict__ W2bT,
                  float* __restrict__ out,
                  const int* __restrict__ nRB, const int* __restrict__ rbExpert,
                  const int* __restrict__ pairsTok, const float* __restrict__ pairsW) {
  __shared__ __align__(16) char smem[33*1024 + 1024];
  gemm_body<1, HH, DD>(smem, blockIdx.x, Hbuf, W2bT, nullptr, out,
                       nRB, rbExpert, pairsTok, pairsW);
}

// ---------------- workspace layout (bytes) ----------------
// 128    po[9]; 192 nRB; 256 rbExpert[72]
// 4096   counts64[64][16] (64-byte strided counters)
// 40960  topW[8192]
// 73728  pairsTok[9216]
// 110592 pairsW[9216]
// 147456 slotOf[8192]
// 180224 topE[8192]
// 262144 Xg      [9216][1024] bf16
// 19136512 Hbuf  [9216][2048] bf16
// 56885248 W1bT  [8][2048][1024] bf16
// 90439680 W2bT  [8][1024][2048] bf16

extern "C" void kernel_launch(void* const* d_in, const int* in_sizes, int n_in,
                              void* d_out, int out_size, void* d_ws, size_t ws_size,
                              hipStream_t stream) {
  const float* x  = (const float*)d_in[0];
  const float* Wg = (const float*)d_in[1];
  const float* W1 = (const float*)d_in[2];
  const float* W2 = (const float*)d_in[3];
  float* out = (float*)d_out;
  char* ws = (char*)d_ws;

  int*   po       = (int*)(ws + 128);
  int*   nRB      = (int*)(ws + 192);
  int*   rbExpert = (int*)(ws + 256);
  int*   counts64 = (int*)(ws + 4096);
  float* topW     = (float*)(ws + 40960);
  int*   pairsTok = (int*)(ws + 73728);
  float* pairsW   = (float*)(ws + 110592);
  int*   slotOf   = (int*)(ws + 147456);
  int*   topE     = (int*)(ws + 180224);
  __hip_bfloat16* Xg   = (__hip_bfloat16*)(ws + 262144);
  __hip_bfloat16* Hbuf = (__hip_bfloat16*)(ws + 19136512);
  __hip_bfloat16* W1bT = (__hip_bfloat16*)(ws + 56885248);
  __hip_bfloat16* W2bT = (__hip_bfloat16*)(ws + 90439680);

  hipMemsetAsync(d_out, 0, (size_t)out_size * sizeof(float), stream);
  hipMemsetAsync(ws, 0, 8192, stream);   // po/nRB + counts64

  mega_kernel<<<NTOK + 4096, 256, 0, stream>>>(x, Wg, topE, topW, counts64, W1, W1bT);
  assign_kernel<<<1, 1024, 0, stream>>>(counts64, topE, topW, po, nRB, rbExpert,
                                        pairsTok, pairsW, slotOf);
  gather_kernel<<<NTOK, 256, 0, stream>>>(x, slotOf, Xg);

  gemm1_fused<<<GG1 + 4096, 256, 0, stream>>>(Xg, W1bT, Hbuf, nRB, rbExpert,
                                              pairsTok, pairsW, W2, W2bT);
  gemm2_kernel<<<GG2, 256, 0, stream>>>(Hbuf, W2bT, out, nRB, rbExpert,
                                        pairsTok, pairsW);
}

// Round 17
// 187.032 us; speedup vs baseline: 1.0632x; 1.0241x over previous
//
#include <hip/hip_runtime.h>
#include <hip/hip_bf16.h>
#include <stdint.h>

#define NTOK 4096
#define DD 1024
#define EE 8
#define HH 2048
#define BM 128
#define BN 128
#define BK 64
#define MAXRB 72
#define RPAD (MAXRB*BM)   // 9216 padded pair rows
#define GG1 (8*9*(HH/BN)) // 1152 gemm1 blocks
#define GG2 (8*9*(DD/BN)) // 576 gemm2 blocks

typedef __attribute__((ext_vector_type(4))) float f32x4;
typedef __attribute__((ext_vector_type(8))) short bf16x8;

__device__ __forceinline__ void gload16(const void* g, void* l) {
  __builtin_amdgcn_global_load_lds((const __attribute__((address_space(1))) unsigned int*)g,
                                   (__attribute__((address_space(3))) unsigned int*)l, 16, 0, 0);
}

__device__ __forceinline__ uint32_t pack_bf2(float lo, float hi) {
  return ((uint32_t)__bfloat16_as_ushort(__float2bfloat16(hi)) << 16)
       |  (uint32_t)__bfloat16_as_ushort(__float2bfloat16(lo));
}

// -------- transpose + f32->bf16 via u32 pair-packing; float4 (16B/lane) reads ----
// in [E][R][C] -> out [E][C][R]. T[c][r/2] = bf16(row 2r)|bf16(row 2r+1).
// Write banks: 4 consecutive banks/lane, wave spread = 2-way (free).
// Read: 8 contiguous u32 -> 2x ds_read_b128 conflict-free; 32B coalesced stores.
__device__ __forceinline__ void transpose_body(uint32_t (*T)[33],
    const float* __restrict__ in, __hip_bfloat16* __restrict__ out,
    int R, int C, int tb) {
  int tilesC = C >> 6;
  int tilesPerE = (R >> 6) * tilesC;
  int e = tb / tilesPerE;
  int rem = tb % tilesPerE;
  int tr = rem / tilesC, tc = rem % tilesC;
  const float* src = in + (size_t)e * R * C + (size_t)(tr*64) * C + tc*64;
  int tid = threadIdx.x;
  int c4 = (tid & 15) << 2;   // 0..60
  int r2 = tid >> 4;          // 0..15
  #pragma unroll
  for (int i = 0; i < 2; ++i) {
    int r = r2 + (i << 4);    // 0..31 -> input rows 2r, 2r+1
    const float* p0 = src + (size_t)(2*r) * C + c4;
    float4 a = *(const float4*)p0;        // row 2r
    float4 b = *(const float4*)(p0 + C);  // row 2r+1
    T[c4+0][r] = pack_bf2(a.x, b.x);
    T[c4+1][r] = pack_bf2(a.y, b.y);
    T[c4+2][r] = pack_bf2(a.z, b.z);
    T[c4+3][r] = pack_bf2(a.w, b.w);
  }
  __syncthreads();
  __hip_bfloat16* dst = out + (size_t)e * R * C + (size_t)(tc*64) * R + tr*64;
  int c  = tid >> 2;
  int ch = (tid & 3) * 8;
  uint32_t v[8];
  #pragma unroll
  for (int j = 0; j < 8; ++j) v[j] = T[c][ch + j];   // 2x ds_read_b128
  uint32_t* dp = (uint32_t*)(dst + (size_t)c * R + ch*2);
  #pragma unroll
  for (int j = 0; j < 8; ++j) dp[j] = v[j];          // 32B coalesced store
}

// ---- mega: router+top2+xbf (blocks 0..4095) + W1 transpose (4096..8191) ----
// Router block computes f64 logits (and emits the token row as bf16 xbf --
// replaces the gather kernel: gemm1 stages A rows from xbf via pairsTok
// indirection, since global_load_lds' global source address is per-lane).
// Thread 0 does softmax/top-2/renorm inline; histogram into 64-way
// cacheline-strided counters (no same-line atomic pileup, R1/R2 lesson).
__global__ __launch_bounds__(256) void mega_kernel(const float* __restrict__ x,
    const float* __restrict__ Wg,
    int* __restrict__ topE, float* __restrict__ topW, int* __restrict__ counts64,
    __hip_bfloat16* __restrict__ xbf,
    const float* __restrict__ W1, __hip_bfloat16* __restrict__ W1bT) {
  __shared__ __align__(16) char smem[8448];
  int b = blockIdx.x;
  if (b < NTOK) {
    int t = b;
    int tid = threadIdx.x;
    const float* xr = x + (size_t)t * DD;
    __hip_bfloat16* xbr = xbf + (size_t)t * DD;
    double acc[EE];
    #pragma unroll
    for (int e = 0; e < EE; ++e) acc[e] = 0.0;
    #pragma unroll
    for (int i = 0; i < DD/256; ++i) {
      int d = tid + i*256;
      float xv = xr[d];
      xbr[d] = __float2bfloat16(xv);               // emit bf16 row (per-wave 128B chunks)
      float4 w0 = *(const float4*)(Wg + (size_t)d*EE);
      float4 w1 = *(const float4*)(Wg + (size_t)d*EE + 4);
      double xd = (double)xv;
      acc[0] += xd * (double)w0.x; acc[1] += xd * (double)w0.y;
      acc[2] += xd * (double)w0.z; acc[3] += xd * (double)w0.w;
      acc[4] += xd * (double)w1.x; acc[5] += xd * (double)w1.y;
      acc[6] += xd * (double)w1.z; acc[7] += xd * (double)w1.w;
    }
    #pragma unroll
    for (int e = 0; e < EE; ++e) {
      double v = acc[e];
      #pragma unroll
      for (int off = 32; off > 0; off >>= 1) v += __shfl_down(v, off, 64);
      acc[e] = v;
    }
    double (*sAcc)[EE] = (double(*)[EE])smem;
    int lane = tid & 63, w = tid >> 6;
    if (lane == 0) {
      #pragma unroll
      for (int e = 0; e < EE; ++e) sAcc[w][e] = acc[e];
    }
    __syncthreads();
    if (tid == 0) {
      double s[EE];
      #pragma unroll
      for (int e = 0; e < EE; ++e)
        s[e] = sAcc[0][e] + sAcc[1][e] + sAcc[2][e] + sAcc[3][e];
      double mx = s[0];
      #pragma unroll
      for (int e = 1; e < EE; ++e) mx = fmax(mx, s[e]);
      double p[EE], Z = 0.0;
      #pragma unroll
      for (int e = 0; e < EE; ++e) { p[e] = exp(s[e] - mx); Z += p[e]; }
      #pragma unroll
      for (int e = 0; e < EE; ++e) p[e] /= Z;
      int i0 = 0;
      #pragma unroll
      for (int e = 1; e < EE; ++e) if (p[e] > p[i0]) i0 = e;
      int i1 = -1;
      #pragma unroll
      for (int e = 0; e < EE; ++e) { if (e == i0) continue; if (i1 < 0 || p[e] > p[i1]) i1 = e; }
      double sm = p[i0] + p[i1] + 1e-8;
      topE[t*2]   = i0; topE[t*2+1] = i1;
      topW[t*2]   = (float)(p[i0] / sm);
      topW[t*2+1] = (float)(p[i1] / sm);
      int slot = (b & 63) * 16;
      atomicAdd(&counts64[slot + i0], 1);
      atomicAdd(&counts64[slot + i1], 1);
    }
  } else {
    transpose_body((uint32_t(*)[33])smem, W1, W1bT, DD, HH, b - NTOK);
  }
}

// -------- setup (counts64 reduce + 128-row padding) + slot assignment: 1 block -----
__global__ __launch_bounds__(1024) void assign_kernel(const int* __restrict__ counts64,
    const int* __restrict__ topE, const float* __restrict__ topW,
    int* __restrict__ po, int* __restrict__ nRB, int* __restrict__ rbExpert,
    int* __restrict__ pairsTok, float* __restrict__ pairsW) {
  __shared__ int cnt[EE];
  __shared__ int base[EE];
  __shared__ int wcnt[16][EE];
  int tid = threadIdx.x, wv = tid >> 6, lane = tid & 63;
  if (tid < EE) {
    int s = 0;
    #pragma unroll
    for (int k = 0; k < 64; ++k) s += counts64[k*16 + tid];
    cnt[tid] = s;
  }
  for (int i = tid; i < RPAD; i += 1024) pairsTok[i] = -1;
  __syncthreads();
  if (tid == 0) {
    int off = 0;
    for (int e = 0; e < EE; ++e) {
      po[e] = off;
      off += ((cnt[e] + BM - 1) / BM) * BM;
    }
    po[EE] = off;
    *nRB = off / BM;
    int rb = 0;
    for (int e = 0; e < EE; ++e) {
      int nb = (cnt[e] + BM - 1) / BM;
      for (int b = 0; b < nb; ++b) rbExpert[rb++] = e;
    }
  }
  __syncthreads();
  if (tid < EE) base[tid] = po[tid];
  __syncthreads();
  for (int it = 0; it < 2*NTOK/1024; ++it) {
    int p = it*1024 + tid;
    int e = topE[p];
    int myrank = 0;
    #pragma unroll
    for (int ee = 0; ee < EE; ++ee) {
      unsigned long long b = __ballot(e == ee);
      if (ee == e) myrank = __popcll(b & ((1ull << lane) - 1ull));
      if (lane == 0) wcnt[wv][ee] = __popcll(b);
    }
    __syncthreads();
    int wbase = 0;
    for (int w2 = 0; w2 < wv; ++w2) wbase += wcnt[w2][e];
    int slot = base[e] + wbase + myrank;
    pairsTok[slot] = p >> 1;
    pairsW[slot]   = topW[p];
    __syncthreads();
    if (tid < EE) {
      int s2 = 0;
      #pragma unroll
      for (int w2 = 0; w2 < 16; ++w2) s2 += wcnt[w2][tid];
      base[tid] += s2;
    }
    __syncthreads();
  }
}

// ---- grouped GEMM body, 128x128 tile, BK=64, single-buffer (R6/R10-proven),
// ---- balanced XCD chunking. smem: As[0..16K), Bs[16K..32K), sTok, sW.
// A-row indirection (EPI==0): row r of the tile reads xbf[pairsTok[rb*128+r]]
// -- the gather kernel is gone; global_load_lds' source addr is per-lane.
// Row base pointers hoisted out of the K-loop (4/thread).
// NOTE (session evidence): this 2-barrier single-buffer loop at 4 blocks/CU is
// the measured optimum of its family (9 structural variants all regressed).
template<int EPI, int KDIM, int NTOT>
__device__ __forceinline__ void gemm_body(char* smem, int bid,
    const __hip_bfloat16* __restrict__ A, const __hip_bfloat16* __restrict__ Ball,
    __hip_bfloat16* __restrict__ Cbf, float* __restrict__ Cf,
    const int* __restrict__ nRB, const int* __restrict__ rbExpert,
    const int* __restrict__ pairsTok, const float* __restrict__ pairsW) {
  int nrb = *nRB;
  int cpx = (nrb + 7) >> 3;
  int xcd = bid & 7;
  int slot = bid >> 3;
  int lr = slot % 9;
  int nb = slot / 9;
  int rb = xcd * cpx + lr;
  if (lr >= cpx || rb >= nrb) return;
  int e = rbExpert[rb];
  const __hip_bfloat16* Bg = Ball + (size_t)e * NTOT * KDIM + (size_t)nb * BN * KDIM;
  __hip_bfloat16* As = (__hip_bfloat16*)smem;
  __hip_bfloat16* Bs = (__hip_bfloat16*)(smem + 16384);
  int*   sTok = (int*)(smem + 32768);
  float* sW   = (float*)(smem + 32768 + 512);
  int tid = threadIdx.x;
  if (EPI == 1 && tid < BM) {
    sTok[tid] = pairsTok[rb*BM + tid];
    sW[tid]   = pairsW[rb*BM + tid];
  }
  int lane = tid & 63;
  int wid = tid >> 6;
  int wr = wid >> 1, wc = wid & 1;
  int l15 = lane & 15;
  int lhi = lane >> 4;
  f32x4 acc[4][4] = {};
  int srow  = tid >> 3;
  int scol8 = (tid & 7) * 8;
  // per-thread A row base pointers (hoisted; EPI==0 indirects through pairsTok)
  const __hip_bfloat16* aRow[4];
  #pragma unroll
  for (int i = 0; i < 4; ++i) {
    int r = srow + 32*i;
    if (EPI == 0) {
      int tok = pairsTok[rb*BM + r];        // L2-hot, 128 distinct values/block
      aRow[i] = A + (size_t)(tok < 0 ? 0 : tok) * KDIM;
    } else {
      aRow[i] = A + (size_t)(rb*BM + r) * KDIM;
    }
  }
  for (int kt = 0; kt < KDIM / BK; ++kt) {
    #pragma unroll
    for (int i = 0; i < 4; ++i) {
      int r = srow + 32*i;
      int sc = scol8 ^ ((r & 7) << 3);   // pre-swizzled global source
      gload16(aRow[i] + kt*BK + sc, (char*)As + i*4096 + tid*16);
      gload16(Bg + (size_t)r * KDIM + kt*BK + sc, (char*)Bs + i*4096 + tid*16);
    }
    __syncthreads();
    #pragma unroll
    for (int kk = 0; kk < 2; ++kk) {
      bf16x8 af[4], bfr[4];
      int kb = kk*64 + lhi*16;
      #pragma unroll
      for (int m = 0; m < 4; ++m) {
        int row = wr*64 + m*16 + l15;
        af[m] = *(const bf16x8*)((const char*)As + row*128 + (kb ^ ((row & 7) << 4)));
      }
      #pragma unroll
      for (int n = 0; n < 4; ++n) {
        int row = wc*64 + n*16 + l15;
        bfr[n] = *(const bf16x8*)((const char*)Bs + row*128 + (kb ^ ((row & 7) << 4)));
      }
      #pragma unroll
      for (int m = 0; m < 4; ++m)
        #pragma unroll
        for (int n = 0; n < 4; ++n)
          acc[m][n] = __builtin_amdgcn_mfma_f32_16x16x32_bf16(af[m], bfr[n], acc[m][n], 0, 0, 0);
    }
    __syncthreads();
  }
  if (EPI == 0) {
    #pragma unroll
    for (int m = 0; m < 4; ++m) {
      int row = rb*BM + wr*64 + m*16 + lhi*4;
      #pragma unroll
      for (int n = 0; n < 4; ++n) {
        int col = nb*BN + wc*64 + n*16 + l15;
        #pragma unroll
        for (int j = 0; j < 4; ++j) {
          float v = fmaxf(acc[m][n][j], 0.0f);
          Cbf[(size_t)(row + j) * NTOT + col] = __float2bfloat16(v * v);
        }
      }
    }
  } else {
    #pragma unroll
    for (int m = 0; m < 4; ++m) {
      int rloc = wr*64 + m*16 + lhi*4;
      #pragma unroll
      for (int j = 0; j < 4; ++j) {
        int tok = sTok[rloc + j];
        if (tok < 0) continue;
        float w = sW[rloc + j];
        #pragma unroll
        for (int n = 0; n < 4; ++n) {
          int col = nb*BN + wc*64 + n*16 + l15;
          atomicAdd(Cf + (size_t)tok * NTOT + col, w * acc[m][n][j]);
        }
      }
    }
  }
}

// ---- GEMM1 fused with W2 transpose: blocks [0,GG1) = gemm, [GG1,GG1+4096) = W2T.
// GEMM1 is latency-bound at ~9% HBM; the W2 transpose rides in its idle
// bandwidth instead of a serial dispatch. Shared mem unioned (33.5KB).
__global__ __launch_bounds__(256, 4)
void gemm1_fused(const __hip_bfloat16* __restrict__ xbf,
                 const __hip_bfloat16* __restrict__ W1bT,
                 __hip_bfloat16* __restrict__ Hbuf,
                 const int* __restrict__ nRB, const int* __restrict__ rbExpert,
                 const int* __restrict__ pairsTok, const float* __restrict__ pairsW,
                 const float* __restrict__ W2, __hip_bfloat16* __restrict__ W2bT) {
  __shared__ __align__(16) char smem[33*1024 + 1024];
  int bid = blockIdx.x;
  if (bid < GG1) {
    gemm_body<0, DD, HH>(smem, bid, xbf, W1bT, Hbuf, nullptr,
                         nRB, rbExpert, pairsTok, pairsW);
  } else {
    transpose_body((uint32_t(*)[33])smem, W2, W2bT, HH, DD, bid - GG1);
  }
}

__global__ __launch_bounds__(256, 4)
void gemm2_kernel(const __hip_bfloat16* __restrict__ Hbuf,
                  const __hip_bfloat16* __restrict__ W2bT,
                  float* __restrict__ out,
                  const int* __restrict__ nRB, const int* __restrict__ rbExpert,
                  const int* __restrict__ pairsTok, const float* __restrict__ pairsW) {
  __shared__ __align__(16) char smem[33*1024 + 1024];
  gemm_body<1, HH, DD>(smem, blockIdx.x, Hbuf, W2bT, nullptr, out,
                       nRB, rbExpert, pairsTok, pairsW);
}

// ---------------- workspace layout (bytes) ----------------
// 128    po[9]; 192 nRB; 256 rbExpert[72]
// 4096   counts64[64][16] (64-byte strided counters)
// 40960  topW[8192]
// 73728  pairsTok[9216]
// 110592 pairsW[9216]
// 180224 topE[8192]
// 262144 xbf    [4096][1024] bf16 (8MB; replaces Xg)
// 19136512 Hbuf  [9216][2048] bf16
// 56885248 W1bT  [8][2048][1024] bf16
// 90439680 W2bT  [8][1024][2048] bf16

extern "C" void kernel_launch(void* const* d_in, const int* in_sizes, int n_in,
                              void* d_out, int out_size, void* d_ws, size_t ws_size,
                              hipStream_t stream) {
  const float* x  = (const float*)d_in[0];
  const float* Wg = (const float*)d_in[1];
  const float* W1 = (const float*)d_in[2];
  const float* W2 = (const float*)d_in[3];
  float* out = (float*)d_out;
  char* ws = (char*)d_ws;

  int*   po       = (int*)(ws + 128);
  int*   nRB      = (int*)(ws + 192);
  int*   rbExpert = (int*)(ws + 256);
  int*   counts64 = (int*)(ws + 4096);
  float* topW     = (float*)(ws + 40960);
  int*   pairsTok = (int*)(ws + 73728);
  float* pairsW   = (float*)(ws + 110592);
  int*   topE     = (int*)(ws + 180224);
  __hip_bfloat16* xbf  = (__hip_bfloat16*)(ws + 262144);
  __hip_bfloat16* Hbuf = (__hip_bfloat16*)(ws + 19136512);
  __hip_bfloat16* W1bT = (__hip_bfloat16*)(ws + 56885248);
  __hip_bfloat16* W2bT = (__hip_bfloat16*)(ws + 90439680);

  hipMemsetAsync(d_out, 0, (size_t)out_size * sizeof(float), stream);
  hipMemsetAsync(ws, 0, 8192, stream);   // po/nRB + counts64

  mega_kernel<<<NTOK + 4096, 256, 0, stream>>>(x, Wg, topE, topW, counts64,
                                               xbf, W1, W1bT);
  assign_kernel<<<1, 1024, 0, stream>>>(counts64, topE, topW, po, nRB, rbExpert,
                                        pairsTok, pairsW);

  gemm1_fused<<<GG1 + 4096, 256, 0, stream>>>(xbf, W1bT, Hbuf, nRB, rbExpert,
                                              pairsTok, pairsW, W2, W2bT);
  gemm2_kernel<<<GG2, 256, 0, stream>>>(Hbuf, W2bT, out, nRB, rbExpert,
                                        pairsTok, pairsW);
}

// Round 19
// 186.154 us; speedup vs baseline: 1.0682x; 1.0047x over previous
//
#include <hip/hip_runtime.h>
#include <hip/hip_bf16.h>
#include <stdint.h>

#define NTOK 4096
#define DD 1024
#define EE 8
#define HH 2048
#define BM 128
#define BN 128
#define BK 64
#define MAXRB 72
#define RPAD (MAXRB*BM)   // 9216 padded pair rows
#define GG1 (8*9*(HH/BN)) // 1152 gemm1 blocks
#define GG2 (8*9*(DD/BN)) // 576 gemm2 blocks

typedef __attribute__((ext_vector_type(4))) float f32x4;
typedef __attribute__((ext_vector_type(8))) short bf16x8;

__device__ __forceinline__ void gload16(const void* g, void* l) {
  __builtin_amdgcn_global_load_lds((const __attribute__((address_space(1))) unsigned int*)g,
                                   (__attribute__((address_space(3))) unsigned int*)l, 16, 0, 0);
}

__device__ __forceinline__ uint32_t pack_bf2(float lo, float hi) {
  return ((uint32_t)__bfloat16_as_ushort(__float2bfloat16(hi)) << 16)
       |  (uint32_t)__bfloat16_as_ushort(__float2bfloat16(lo));
}

// -------- transpose + f32->bf16 via u32 pair-packing; float4 (16B/lane) reads ----
// in [E][R][C] -> out [E][C][R]. T[c][r/2] = bf16(row 2r)|bf16(row 2r+1).
// Write banks: 4 consecutive banks/lane, wave spread = 2-way (free).
// Read: 8 contiguous u32 -> 2x ds_read_b128 conflict-free; 32B coalesced stores.
__device__ __forceinline__ void transpose_body(uint32_t (*T)[33],
    const float* __restrict__ in, __hip_bfloat16* __restrict__ out,
    int R, int C, int tb) {
  int tilesC = C >> 6;
  int tilesPerE = (R >> 6) * tilesC;
  int e = tb / tilesPerE;
  int rem = tb % tilesPerE;
  int tr = rem / tilesC, tc = rem % tilesC;
  const float* src = in + (size_t)e * R * C + (size_t)(tr*64) * C + tc*64;
  int tid = threadIdx.x;
  int c4 = (tid & 15) << 2;   // 0..60
  int r2 = tid >> 4;          // 0..15
  #pragma unroll
  for (int i = 0; i < 2; ++i) {
    int r = r2 + (i << 4);    // 0..31 -> input rows 2r, 2r+1
    const float* p0 = src + (size_t)(2*r) * C + c4;
    float4 a = *(const float4*)p0;        // row 2r
    float4 b = *(const float4*)(p0 + C);  // row 2r+1
    T[c4+0][r] = pack_bf2(a.x, b.x);
    T[c4+1][r] = pack_bf2(a.y, b.y);
    T[c4+2][r] = pack_bf2(a.z, b.z);
    T[c4+3][r] = pack_bf2(a.w, b.w);
  }
  __syncthreads();
  __hip_bfloat16* dst = out + (size_t)e * R * C + (size_t)(tc*64) * R + tr*64;
  int c  = tid >> 2;
  int ch = (tid & 3) * 8;
  uint32_t v[8];
  #pragma unroll
  for (int j = 0; j < 8; ++j) v[j] = T[c][ch + j];   // 2x ds_read_b128
  uint32_t* dp = (uint32_t*)(dst + (size_t)c * R + ch*2);
  #pragma unroll
  for (int j = 0; j < 8; ++j) dp[j] = v[j];          // 32B coalesced store
}

// ---- mega: router+top2+xbf (blocks 0..4095) + W1 transpose (4096..8191) ----
// Router block computes f64 logits (and emits the token row as bf16 xbf --
// replaces the gather kernel: gemm1 stages A rows from xbf via pairsTok
// indirection, since global_load_lds' global source address is per-lane).
// Thread 0 does softmax/top-2/renorm inline; histogram into 64-way
// cacheline-strided counters (no same-line atomic pileup, R1/R2 lesson).
__global__ __launch_bounds__(256) void mega_kernel(const float* __restrict__ x,
    const float* __restrict__ Wg,
    int* __restrict__ topE, float* __restrict__ topW, int* __restrict__ counts64,
    __hip_bfloat16* __restrict__ xbf,
    const float* __restrict__ W1, __hip_bfloat16* __restrict__ W1bT) {
  __shared__ __align__(16) char smem[8448];
  int b = blockIdx.x;
  if (b < NTOK) {
    int t = b;
    int tid = threadIdx.x;
    const float* xr = x + (size_t)t * DD;
    __hip_bfloat16* xbr = xbf + (size_t)t * DD;
    double acc[EE];
    #pragma unroll
    for (int e = 0; e < EE; ++e) acc[e] = 0.0;
    #pragma unroll
    for (int i = 0; i < DD/256; ++i) {
      int d = tid + i*256;
      float xv = xr[d];
      xbr[d] = __float2bfloat16(xv);               // emit bf16 row
      float4 w0 = *(const float4*)(Wg + (size_t)d*EE);
      float4 w1 = *(const float4*)(Wg + (size_t)d*EE + 4);
      double xd = (double)xv;
      acc[0] += xd * (double)w0.x; acc[1] += xd * (double)w0.y;
      acc[2] += xd * (double)w0.z; acc[3] += xd * (double)w0.w;
      acc[4] += xd * (double)w1.x; acc[5] += xd * (double)w1.y;
      acc[6] += xd * (double)w1.z; acc[7] += xd * (double)w1.w;
    }
    #pragma unroll
    for (int e = 0; e < EE; ++e) {
      double v = acc[e];
      #pragma unroll
      for (int off = 32; off > 0; off >>= 1) v += __shfl_down(v, off, 64);
      acc[e] = v;
    }
    double (*sAcc)[EE] = (double(*)[EE])smem;
    int lane = tid & 63, w = tid >> 6;
    if (lane == 0) {
      #pragma unroll
      for (int e = 0; e < EE; ++e) sAcc[w][e] = acc[e];
    }
    __syncthreads();
    if (tid == 0) {
      double s[EE];
      #pragma unroll
      for (int e = 0; e < EE; ++e)
        s[e] = sAcc[0][e] + sAcc[1][e] + sAcc[2][e] + sAcc[3][e];
      double mx = s[0];
      #pragma unroll
      for (int e = 1; e < EE; ++e) mx = fmax(mx, s[e]);
      double p[EE], Z = 0.0;
      #pragma unroll
      for (int e = 0; e < EE; ++e) { p[e] = exp(s[e] - mx); Z += p[e]; }
      #pragma unroll
      for (int e = 0; e < EE; ++e) p[e] /= Z;
      int i0 = 0;
      #pragma unroll
      for (int e = 1; e < EE; ++e) if (p[e] > p[i0]) i0 = e;
      int i1 = -1;
      #pragma unroll
      for (int e = 0; e < EE; ++e) { if (e == i0) continue; if (i1 < 0 || p[e] > p[i1]) i1 = e; }
      double sm = p[i0] + p[i1] + 1e-8;
      topE[t*2]   = i0; topE[t*2+1] = i1;
      topW[t*2]   = (float)(p[i0] / sm);
      topW[t*2+1] = (float)(p[i1] / sm);
      int slot = (b & 63) * 16;
      atomicAdd(&counts64[slot + i0], 1);
      atomicAdd(&counts64[slot + i1], 1);
    }
  } else {
    transpose_body((uint32_t(*)[33])smem, W1, W1bT, DD, HH, b - NTOK);
  }
}

// -------- setup (counts64 reduce + 128-row padding) + slot assignment: 1 block -----
__global__ __launch_bounds__(1024) void assign_kernel(const int* __restrict__ counts64,
    const int* __restrict__ topE, const float* __restrict__ topW,
    int* __restrict__ po, int* __restrict__ nRB, int* __restrict__ rbExpert,
    int* __restrict__ pairsTok, float* __restrict__ pairsW) {
  __shared__ int cnt[EE];
  __shared__ int base[EE];
  __shared__ int wcnt[16][EE];
  int tid = threadIdx.x, wv = tid >> 6, lane = tid & 63;
  if (tid < EE) {
    int s = 0;
    #pragma unroll
    for (int k = 0; k < 64; ++k) s += counts64[k*16 + tid];
    cnt[tid] = s;
  }
  for (int i = tid; i < RPAD; i += 1024) pairsTok[i] = -1;
  __syncthreads();
  if (tid == 0) {
    int off = 0;
    for (int e = 0; e < EE; ++e) {
      po[e] = off;
      off += ((cnt[e] + BM - 1) / BM) * BM;
    }
    po[EE] = off;
    *nRB = off / BM;
    int rb = 0;
    for (int e = 0; e < EE; ++e) {
      int nb = (cnt[e] + BM - 1) / BM;
      for (int b = 0; b < nb; ++b) rbExpert[rb++] = e;
    }
  }
  __syncthreads();
  if (tid < EE) base[tid] = po[tid];
  __syncthreads();
  for (int it = 0; it < 2*NTOK/1024; ++it) {
    int p = it*1024 + tid;
    int e = topE[p];
    int myrank = 0;
    #pragma unroll
    for (int ee = 0; ee < EE; ++ee) {
      unsigned long long b = __ballot(e == ee);
      if (ee == e) myrank = __popcll(b & ((1ull << lane) - 1ull));
      if (lane == 0) wcnt[wv][ee] = __popcll(b);
    }
    __syncthreads();
    int wbase = 0;
    for (int w2 = 0; w2 < wv; ++w2) wbase += wcnt[w2][e];
    int slot = base[e] + wbase + myrank;
    pairsTok[slot] = p >> 1;
    pairsW[slot]   = topW[p];
    __syncthreads();
    if (tid < EE) {
      int s2 = 0;
      #pragma unroll
      for (int w2 = 0; w2 < 16; ++w2) s2 += wcnt[w2][tid];
      base[tid] += s2;
    }
    __syncthreads();
  }
}

// ---- grouped GEMM body, 128x128 tile, BK=64, single-buffer (R6/R10-proven),
// ---- balanced XCD chunking. smem: As[0..16K), Bs[16K..32K), sTok, sW.
// A-row indirection (EPI==0): row r of the tile reads xbf[pairsTok[rb*128+r]]
// -- the gather kernel is gone; global_load_lds' source addr is per-lane.
// Row base pointers hoisted out of the K-loop (4/thread).
// NOTE (session evidence): this 2-barrier single-buffer loop at 4 blocks/CU is
// the measured optimum of its family. Beaten variants: sync-dbuf@2blk (98us),
// raw-barrier-dbuf@2blk (90us), counted-vmcnt BK=32 dbuf@4blk (77us, FETCH 2x),
// iso-TLP 512-thr counted-vmcnt dbuf (RACE, absmax 0.088), BN=64 (flat),
// K-split (worse), producer-consumer fusion (worse), 256^2 8-phase port (worse).
template<int EPI, int KDIM, int NTOT>
__device__ __forceinline__ void gemm_body(char* smem, int bid,
    const __hip_bfloat16* __restrict__ A, const __hip_bfloat16* __restrict__ Ball,
    __hip_bfloat16* __restrict__ Cbf, float* __restrict__ Cf,
    const int* __restrict__ nRB, const int* __restrict__ rbExpert,
    const int* __restrict__ pairsTok, const float* __restrict__ pairsW) {
  int nrb = *nRB;
  int cpx = (nrb + 7) >> 3;
  int xcd = bid & 7;
  int slot = bid >> 3;
  int lr = slot % 9;
  int nb = slot / 9;
  int rb = xcd * cpx + lr;
  if (lr >= cpx || rb >= nrb) return;
  int e = rbExpert[rb];
  const __hip_bfloat16* Bg = Ball + (size_t)e * NTOT * KDIM + (size_t)nb * BN * KDIM;
  __hip_bfloat16* As = (__hip_bfloat16*)smem;
  __hip_bfloat16* Bs = (__hip_bfloat16*)(smem + 16384);
  int*   sTok = (int*)(smem + 32768);
  float* sW   = (float*)(smem + 32768 + 512);
  int tid = threadIdx.x;
  if (EPI == 1 && tid < BM) {
    sTok[tid] = pairsTok[rb*BM + tid];
    sW[tid]   = pairsW[rb*BM + tid];
  }
  int lane = tid & 63;
  int wid = tid >> 6;
  int wr = wid >> 1, wc = wid & 1;
  int l15 = lane & 15;
  int lhi = lane >> 4;
  f32x4 acc[4][4] = {};
  int srow  = tid >> 3;
  int scol8 = (tid & 7) * 8;
  // per-thread A row base pointers (hoisted; EPI==0 indirects through pairsTok)
  const __hip_bfloat16* aRow[4];
  #pragma unroll
  for (int i = 0; i < 4; ++i) {
    int r = srow + 32*i;
    if (EPI == 0) {
      int tok = pairsTok[rb*BM + r];        // L2-hot, 128 distinct values/block
      aRow[i] = A + (size_t)(tok < 0 ? 0 : tok) * KDIM;
    } else {
      aRow[i] = A + (size_t)(rb*BM + r) * KDIM;
    }
  }
  for (int kt = 0; kt < KDIM / BK; ++kt) {
    #pragma unroll
    for (int i = 0; i < 4; ++i) {
      int r = srow + 32*i;
      int sc = scol8 ^ ((r & 7) << 3);   // pre-swizzled global source
      gload16(aRow[i] + kt*BK + sc, (char*)As + i*4096 + tid*16);
      gload16(Bg + (size_t)r * KDIM + kt*BK + sc, (char*)Bs + i*4096 + tid*16);
    }
    __syncthreads();
    #pragma unroll
    for (int kk = 0; kk < 2; ++kk) {
      bf16x8 af[4], bfr[4];
      int kb = kk*64 + lhi*16;
      #pragma unroll
      for (int m = 0; m < 4; ++m) {
        int row = wr*64 + m*16 + l15;
        af[m] = *(const bf16x8*)((const char*)As + row*128 + (kb ^ ((row & 7) << 4)));
      }
      #pragma unroll
      for (int n = 0; n < 4; ++n) {
        int row = wc*64 + n*16 + l15;
        bfr[n] = *(const bf16x8*)((const char*)Bs + row*128 + (kb ^ ((row & 7) << 4)));
      }
      #pragma unroll
      for (int m = 0; m < 4; ++m)
        #pragma unroll
        for (int n = 0; n < 4; ++n)
          acc[m][n] = __builtin_amdgcn_mfma_f32_16x16x32_bf16(af[m], bfr[n], acc[m][n], 0, 0, 0);
    }
    __syncthreads();
  }
  if (EPI == 0) {
    #pragma unroll
    for (int m = 0; m < 4; ++m) {
      int row = rb*BM + wr*64 + m*16 + lhi*4;
      #pragma unroll
      for (int n = 0; n < 4; ++n) {
        int col = nb*BN + wc*64 + n*16 + l15;
        #pragma unroll
        for (int j = 0; j < 4; ++j) {
          float v = fmaxf(acc[m][n][j], 0.0f);
          Cbf[(size_t)(row + j) * NTOT + col] = __float2bfloat16(v * v);
        }
      }
    }
  } else {
    #pragma unroll
    for (int m = 0; m < 4; ++m) {
      int rloc = wr*64 + m*16 + lhi*4;
      #pragma unroll
      for (int j = 0; j < 4; ++j) {
        int tok = sTok[rloc + j];
        if (tok < 0) continue;
        float w = sW[rloc + j];
        #pragma unroll
        for (int n = 0; n < 4; ++n) {
          int col = nb*BN + wc*64 + n*16 + l15;
          atomicAdd(Cf + (size_t)tok * NTOT + col, w * acc[m][n][j]);
        }
      }
    }
  }
}

// ---- GEMM1 fused with W2 transpose: blocks [0,GG1) = gemm, [GG1,GG1+4096) = W2T.
// GEMM1 is latency-bound at ~9% HBM; the W2 transpose rides in its idle
// bandwidth instead of a serial dispatch. Shared mem unioned (33.5KB).
__global__ __launch_bounds__(256, 4)
void gemm1_fused(const __hip_bfloat16* __restrict__ xbf,
                 const __hip_bfloat16* __restrict__ W1bT,
                 __hip_bfloat16* __restrict__ Hbuf,
                 const int* __restrict__ nRB, const int* __restrict__ rbExpert,
                 const int* __restrict__ pairsTok, const float* __restrict__ pairsW,
                 const float* __restrict__ W2, __hip_bfloat16* __restrict__ W2bT) {
  __shared__ __align__(16) char smem[33*1024 + 1024];
  int bid = blockIdx.x;
  if (bid < GG1) {
    gemm_body<0, DD, HH>(smem, bid, xbf, W1bT, Hbuf, nullptr,
                         nRB, rbExpert, pairsTok, pairsW);
  } else {
    transpose_body((uint32_t(*)[33])smem, W2, W2bT, HH, DD, bid - GG1);
  }
}

__global__ __launch_bounds__(256, 4)
void gemm2_kernel(const __hip_bfloat16* __restrict__ Hbuf,
                  const __hip_bfloat16* __restrict__ W2bT,
                  float* __restrict__ out,
                  const int* __restrict__ nRB, const int* __restrict__ rbExpert,
                  const int* __restrict__ pairsTok, const float* __restrict__ pairsW) {
  __shared__ __align__(16) char smem[33*1024 + 1024];
  gemm_body<1, HH, DD>(smem, blockIdx.x, Hbuf, W2bT, nullptr, out,
                       nRB, rbExpert, pairsTok, pairsW);
}

// ---------------- workspace layout (bytes) ----------------
// 128    po[9]; 192 nRB; 256 rbExpert[72]
// 4096   counts64[64][16] (64-byte strided counters)
// 40960  topW[8192]
// 73728  pairsTok[9216]
// 110592 pairsW[9216]
// 180224 topE[8192]
// 262144 xbf    [4096][1024] bf16 (8MB)
// 19136512 Hbuf  [9216][2048] bf16
// 56885248 W1bT  [8][2048][1024] bf16
// 90439680 W2bT  [8][1024][2048] bf16

extern "C" void kernel_launch(void* const* d_in, const int* in_sizes, int n_in,
                              void* d_out, int out_size, void* d_ws, size_t ws_size,
                              hipStream_t stream) {
  const float* x  = (const float*)d_in[0];
  const float* Wg = (const float*)d_in[1];
  const float* W1 = (const float*)d_in[2];
  const float* W2 = (const float*)d_in[3];
  float* out = (float*)d_out;
  char* ws = (char*)d_ws;

  int*   po       = (int*)(ws + 128);
  int*   nRB      = (int*)(ws + 192);
  int*   rbExpert = (int*)(ws + 256);
  int*   counts64 = (int*)(ws + 4096);
  float* topW     = (float*)(ws + 40960);
  int*   pairsTok = (int*)(ws + 73728);
  float* pairsW   = (float*)(ws + 110592);
  int*   topE     = (int*)(ws + 180224);
  __hip_bfloat16* xbf  = (__hip_bfloat16*)(ws + 262144);
  __hip_bfloat16* Hbuf = (__hip_bfloat16*)(ws + 19136512);
  __hip_bfloat16* W1bT = (__hip_bfloat16*)(ws + 56885248);
  __hip_bfloat16* W2bT = (__hip_bfloat16*)(ws + 90439680);

  hipMemsetAsync(d_out, 0, (size_t)out_size * sizeof(float), stream);
  hipMemsetAsync(ws, 0, 8192, stream);   // po/nRB + counts64

  mega_kernel<<<NTOK + 4096, 256, 0, stream>>>(x, Wg, topE, topW, counts64,
                                               xbf, W1, W1bT);
  assign_kernel<<<1, 1024, 0, stream>>>(counts64, topE, topW, po, nRB, rbExpert,
                                        pairsTok, pairsW);

  gemm1_fused<<<GG1 + 4096, 256, 0, stream>>>(xbf, W1bT, Hbuf, nRB, rbExpert,
                                              pairsTok, pairsW, W2, W2bT);
  gemm2_kernel<<<GG2, 256, 0, stream>>>(Hbuf, W2bT, out, nRB, rbExpert,
                                        pairsTok, pairsW);
}